// Round 4
// baseline (17964.909 us; speedup 1.0000x reference)
//
#include <hip/hip_runtime.h>

#define SEQ   8192
#define VOCAB 128000
#define L     64
#define NCH   128   // SEQ / L

// ws layout (float offsets)
#define OFF_WT   0          // WT[k][v]   : [20][128000] transposed W_i2o (10.24 MB)
#define OFF_CMB  2560000    // CmbT[k][t] : [20][8192] combined, k-major (640 KB)
#define OFF_CVEC 2723840    // cvecT[k][m][i] : [64][128][10]
#define OFF_AMAX 2805760    // amax[t] : 8192 x u64 packed (key<<32 | VOCAB-idx)
// total = 2,822,144 floats = 11.3 MB

// ---------------------------------------------------------------------------
// K1: gather embeddings -> CmbT rows 0..9; cvec_t = W_i2h[:,:10]*w_t + b_i2h;
//     zero the atomic-argmax array.
// ---------------------------------------------------------------------------
__global__ void k_embed(const int* __restrict__ ix, const float* __restrict__ emb,
                        const float* __restrict__ Wih, const float* __restrict__ bih,
                        float* __restrict__ ws) {
    int t = blockIdx.x * blockDim.x + threadIdx.x;
    if (t >= SEQ) return;

    ((unsigned long long*)(ws + OFF_AMAX))[t] = 0ULL;   // zero packed argmax

    int id = ix[t];
    float w[10];
    const float2* ep = (const float2*)(emb + (long long)id * 10);
#pragma unroll
    for (int j = 0; j < 5; j++) ((float2*)w)[j] = ep[j];

    // CmbT[j][t] = w[j]  (coalesced: consecutive t -> consecutive addr)
#pragma unroll
    for (int j = 0; j < 10; j++) ws[OFF_CMB + j * SEQ + t] = w[j];

    int m = t >> 6, k = t & 63;
    float* cv = ws + OFF_CVEC + (k * NCH + m) * 10;
#pragma unroll
    for (int i = 0; i < 10; i++) {
        float s = bih[i];
#pragma unroll
        for (int j = 0; j < 10; j++) s += Wih[i * 20 + j] * w[j];
        cv[i] = s;
    }
}

// ---------------------------------------------------------------------------
// K2: transpose W_i2o (VOCAB x 20) -> WT (20 x VOCAB)
// ---------------------------------------------------------------------------
__global__ void k_transpose(const float* __restrict__ Wio, float* __restrict__ ws) {
    int v = blockIdx.x * blockDim.x + threadIdx.x;
    if (v >= VOCAB) return;
    const float4* r = (const float4*)(Wio + (long long)v * 20);
    float vals[20];
#pragma unroll
    for (int q = 0; q < 5; q++) ((float4*)vals)[q] = r[q];
    float* WT = ws + OFF_WT;
#pragma unroll
    for (int k = 0; k < 20; k++) WT[k * VOCAB + v] = vals[k];
}

// ---------------------------------------------------------------------------
// K3: blocked scan of h_{t+1} = A h_t + c_t; writes h_t into CmbT rows 10..19
// ---------------------------------------------------------------------------
__global__ void k_scan(const float* __restrict__ Wih, float* __restrict__ ws) {
    __shared__ float P[100], Q[100];
    __shared__ float Dl[NCH][10];
    __shared__ float Hst[NCH][10];
    __shared__ float Hl[10];
    int tid = threadIdx.x;

    float Ar[10][10];
#pragma unroll
    for (int i = 0; i < 10; i++)
#pragma unroll
        for (int j = 0; j < 10; j++) Ar[i][j] = Wih[i * 20 + 10 + j];

    // ---- phase A: each thread = one chunk, from zero state ----
    {
        int m = tid;
        float h[10];
#pragma unroll
        for (int i = 0; i < 10; i++) h[i] = 0.f;
        const float* cvb = ws + OFF_CVEC;
        for (int k = 0; k < L; k++) {
            const float* c = cvb + (k * NCH + m) * 10;
            float nh[10];
#pragma unroll
            for (int i = 0; i < 10; i++) {
                float s = c[i];
#pragma unroll
                for (int j = 0; j < 10; j++) s += Ar[i][j] * h[j];
                nh[i] = s;
            }
#pragma unroll
            for (int i = 0; i < 10; i++) h[i] = nh[i];
        }
#pragma unroll
        for (int i = 0; i < 10; i++) Dl[m][i] = h[i];
    }

    // ---- phase B1: A^64 via 6 squarings ----
    if (tid < 100) P[tid] = Wih[(tid / 10) * 20 + 10 + (tid % 10)];
    __syncthreads();
    for (int it = 0; it < 6; it++) {
        if (tid < 100) {
            int i = tid / 10, j = tid % 10;
            float s = 0.f;
#pragma unroll
            for (int k = 0; k < 10; k++) s += P[i * 10 + k] * P[k * 10 + j];
            Q[tid] = s;
        }
        __syncthreads();
        if (tid < 100) P[tid] = Q[tid];
        __syncthreads();
    }

    // ---- phase B2: chunk-boundary scan (lanes 0..9, wave-lockstep) ----
    if (tid < 10) Hl[tid] = 0.f;
    __syncthreads();
    if (tid < 10) {
        int i = tid;
        float a64[10];
#pragma unroll
        for (int j = 0; j < 10; j++) a64[j] = P[i * 10 + j];
        float hc = 0.f;
        for (int m = 0; m < NCH; m++) {
            Hst[m][i] = hc;
            float s = Dl[m][i];
#pragma unroll
            for (int j = 0; j < 10; j++) s += a64[j] * Hl[j];
            Hl[i] = s;
            hc = s;
        }
    }
    __syncthreads();

    // ---- phase C: re-run with true starts; CmbT[10+i][m*64+k] = h_t ----
    {
        int m = tid;
        float h[10];
#pragma unroll
        for (int i = 0; i < 10; i++) h[i] = Hst[m][i];
        const float* cvb = ws + OFF_CVEC;
        for (int k = 0; k < L; k++) {
            int tg = m * 64 + k;
#pragma unroll
            for (int i = 0; i < 10; i++) ws[OFF_CMB + (10 + i) * SEQ + tg] = h[i];
            const float* c = cvb + (k * NCH + m) * 10;
            float nh[10];
#pragma unroll
            for (int i = 0; i < 10; i++) {
                float s = c[i];
#pragma unroll
                for (int j = 0; j < 10; j++) s += Ar[i][j] * h[j];
                nh[i] = s;
            }
#pragma unroll
            for (int i = 0; i < 10; i++) h[i] = nh[i];
        }
    }
}

// ---------------------------------------------------------------------------
// K4: fused logits + argmax. W slice (512 v, 40 KB) in LDS; c read directly
// from global (wave-uniform broadcast dwordx4, L2-resident, VMEM pipe).
// Grid: 2000 = 250 v-slices x 8 t-quarters (1024 t). Block: 4 waves; per
// 64-t pass each wave owns 16 t and sweeps all 512 v as 2 subs of
// acc[16][4] (proven no-spill shape). No barriers in the main loop.
// Argmax merged via packed u64 atomicMax (exact jnp.argmax semantics).
// ---------------------------------------------------------------------------
__global__ __launch_bounds__(256, 3)
void k_logits(const float* __restrict__ ws, const float* __restrict__ bio,
              unsigned long long* __restrict__ amax) {
    __shared__ float Wl[20 * 512];        // 40 KB

    int tid = threadIdx.x;
    int vt  = tid & 63;
    int tg  = tid >> 6;

    int b     = blockIdx.x;
    int sl    = b % 250;                  // v-slice (512 v)
    int tq    = b / 250;                  // t-quarter (1024 t)
    int tbase = tq * 1024;

    const float4* WT4  = (const float4*)(ws + OFF_WT);
    const float4* CMB4 = (const float4*)(ws + OFF_CMB);
    const float4* B4   = (const float4*)bio;
    float4* Wl4 = (float4*)Wl;

    // ---- stage W slice: 2560 float4, 10 per thread ----
#pragma unroll
    for (int r = 0; r < 10; r++) {
        int F = tid + 256 * r;            // = k*128 + j
        int k = F >> 7, j = F & 127;
        Wl4[F] = WT4[k * 32000 + sl * 128 + j];
    }
    __syncthreads();

    float4 b4a = B4[sl * 128 + vt];
    float4 b4b = B4[sl * 128 + 64 + vt];
    int v0a = sl * 512 + 4 * vt;
    int v0b = v0a + 256;

    for (int p = 0; p < 16; p++) {
        int tb = tbase + p * 64 + tg * 16;   // this wave's 16 t
        int tb4 = tb >> 2;

        float best[16];
        int   bidx[16];
#pragma unroll
        for (int t = 0; t < 16; t++) { best[t] = -1e30f; bidx[t] = 0; }

#pragma unroll
        for (int sub = 0; sub < 2; sub++) {
            float4 b4 = (sub == 0) ? b4a : b4b;
            int    v0 = (sub == 0) ? v0a : v0b;

            float acc[16][4];
#pragma unroll
            for (int t = 0; t < 16; t++) {
                acc[t][0] = b4.x; acc[t][1] = b4.y; acc[t][2] = b4.z; acc[t][3] = b4.w;
            }
#pragma unroll
            for (int k = 0; k < 20; k++) {
                float4 w4 = Wl4[k * 128 + sub * 64 + vt];
                const float4* cp = CMB4 + k * 2048 + tb4;   // wave-uniform
                float cvv[16];
                ((float4*)cvv)[0] = cp[0]; ((float4*)cvv)[1] = cp[1];
                ((float4*)cvv)[2] = cp[2]; ((float4*)cvv)[3] = cp[3];
#pragma unroll
                for (int t = 0; t < 16; t++) {
                    acc[t][0] += cvv[t] * w4.x;
                    acc[t][1] += cvv[t] * w4.y;
                    acc[t][2] += cvv[t] * w4.z;
                    acc[t][3] += cvv[t] * w4.w;
                }
            }
#pragma unroll
            for (int t = 0; t < 16; t++) {
#pragma unroll
                for (int j = 0; j < 4; j++) {
                    if (acc[t][j] > best[t]) { best[t] = acc[t][j]; bidx[t] = v0 + j; }
                }
            }
        }

        // cross-lane argmax (64 lanes hold disjoint v; ties -> lower idx)
#pragma unroll
        for (int t = 0; t < 16; t++) {
            float bv = best[t]; int bi = bidx[t];
            for (int off = 32; off > 0; off >>= 1) {
                float ov = __shfl_down(bv, off);
                int   oi = __shfl_down(bi, off);
                if (ov > bv || (ov == bv && oi < bi)) { bv = ov; bi = oi; }
            }
            if (vt == 0) {
                unsigned int u = __float_as_uint(bv);
                unsigned int key = (u & 0x80000000u) ? ~u : (u | 0x80000000u);
                unsigned long long packed =
                    ((unsigned long long)key << 32) | (unsigned int)(VOCAB - bi);
                atomicMax(&amax[tb + t], packed);
            }
        }
    }
}

// ---------------------------------------------------------------------------
// K5: unpack argmax -> float index
// ---------------------------------------------------------------------------
__global__ void k_out(const unsigned long long* __restrict__ amax,
                      float* __restrict__ out) {
    int t = blockIdx.x * blockDim.x + threadIdx.x;
    if (t >= SEQ) return;
    unsigned long long p = amax[t];
    int idx = VOCAB - (int)(p & 0xFFFFFFFFu);
    out[t] = (float)idx;
}

// ---------------------------------------------------------------------------
extern "C" void kernel_launch(void* const* d_in, const int* in_sizes, int n_in,
                              void* d_out, int out_size, void* d_ws, size_t ws_size,
                              hipStream_t stream) {
    (void)in_sizes; (void)n_in; (void)out_size; (void)ws_size;
    const int*   ix  = (const int*)d_in[0];
    const float* emb = (const float*)d_in[1];
    const float* Wih = (const float*)d_in[2];
    const float* bih = (const float*)d_in[3];
    const float* Wio = (const float*)d_in[4];
    const float* bio = (const float*)d_in[5];
    float* out = (float*)d_out;
    float* ws  = (float*)d_ws;
    unsigned long long* amax = (unsigned long long*)(ws + OFF_AMAX);

    hipLaunchKernelGGL(k_embed,     dim3(SEQ / 256), dim3(256), 0, stream, ix, emb, Wih, bih, ws);
    hipLaunchKernelGGL(k_transpose, dim3(VOCAB / 256), dim3(256), 0, stream, Wio, ws);
    hipLaunchKernelGGL(k_scan,      dim3(1), dim3(128), 0, stream, Wih, ws);
    hipLaunchKernelGGL(k_logits,    dim3(2000), dim3(256), 0, stream, ws, bio, amax);
    hipLaunchKernelGGL(k_out,       dim3(SEQ / 256), dim3(256), 0, stream, amax, out);
}

// Round 5
// 2135.164 us; speedup vs baseline: 8.4138x; 8.4138x over previous
//
#include <hip/hip_runtime.h>

#define SEQ   8192
#define VOCAB 128000
#define L     64
#define NCH   128   // SEQ / L

// ws layout (float offsets)
#define OFF_WT   0          // WT[k][v]   : [20][128000] transposed W_i2o (10.24 MB)
#define OFF_CMB  2560000    // CmbT[k][t] : [20][8192] combined, k-major (640 KB)
#define OFF_CVEC 2723840    // cvecT[k][m][i] : [64][128][10]
#define OFF_AMAX 2805760    // amax[t] : 8192 x u64 packed (key<<32 | VOCAB-idx)
// total = 2,822,144 floats = 11.3 MB

// ---------------------------------------------------------------------------
// K1: gather embeddings -> CmbT rows 0..9; cvec_t = W_i2h[:,:10]*w_t + b_i2h;
//     zero the atomic-argmax array.
// ---------------------------------------------------------------------------
__global__ void k_embed(const int* __restrict__ ix, const float* __restrict__ emb,
                        const float* __restrict__ Wih, const float* __restrict__ bih,
                        float* __restrict__ ws) {
    int t = blockIdx.x * blockDim.x + threadIdx.x;
    if (t >= SEQ) return;

    ((unsigned long long*)(ws + OFF_AMAX))[t] = 0ULL;   // zero packed argmax

    int id = ix[t];
    float w[10];
    const float2* ep = (const float2*)(emb + (long long)id * 10);
#pragma unroll
    for (int j = 0; j < 5; j++) ((float2*)w)[j] = ep[j];

    // CmbT[j][t] = w[j]  (coalesced: consecutive t -> consecutive addr)
#pragma unroll
    for (int j = 0; j < 10; j++) ws[OFF_CMB + j * SEQ + t] = w[j];

    int m = t >> 6, k = t & 63;
    float* cv = ws + OFF_CVEC + (k * NCH + m) * 10;
#pragma unroll
    for (int i = 0; i < 10; i++) {
        float s = bih[i];
#pragma unroll
        for (int j = 0; j < 10; j++) s += Wih[i * 20 + j] * w[j];
        cv[i] = s;
    }
}

// ---------------------------------------------------------------------------
// K2: transpose W_i2o (VOCAB x 20) -> WT (20 x VOCAB)
// ---------------------------------------------------------------------------
__global__ void k_transpose(const float* __restrict__ Wio, float* __restrict__ ws) {
    int v = blockIdx.x * blockDim.x + threadIdx.x;
    if (v >= VOCAB) return;
    const float4* r = (const float4*)(Wio + (long long)v * 20);
    float vals[20];
#pragma unroll
    for (int q = 0; q < 5; q++) ((float4*)vals)[q] = r[q];
    float* WT = ws + OFF_WT;
#pragma unroll
    for (int k = 0; k < 20; k++) WT[k * VOCAB + v] = vals[k];
}

// ---------------------------------------------------------------------------
// K3: blocked scan of h_{t+1} = A h_t + c_t; writes h_t into CmbT rows 10..19
// ---------------------------------------------------------------------------
__global__ void k_scan(const float* __restrict__ Wih, float* __restrict__ ws) {
    __shared__ float P[100], Q[100];
    __shared__ float Dl[NCH][10];
    __shared__ float Hst[NCH][10];
    __shared__ float Hl[10];
    int tid = threadIdx.x;

    float Ar[10][10];
#pragma unroll
    for (int i = 0; i < 10; i++)
#pragma unroll
        for (int j = 0; j < 10; j++) Ar[i][j] = Wih[i * 20 + 10 + j];

    // ---- phase A: each thread = one chunk, from zero state ----
    {
        int m = tid;
        float h[10];
#pragma unroll
        for (int i = 0; i < 10; i++) h[i] = 0.f;
        const float* cvb = ws + OFF_CVEC;
        for (int k = 0; k < L; k++) {
            const float* c = cvb + (k * NCH + m) * 10;
            float nh[10];
#pragma unroll
            for (int i = 0; i < 10; i++) {
                float s = c[i];
#pragma unroll
                for (int j = 0; j < 10; j++) s += Ar[i][j] * h[j];
                nh[i] = s;
            }
#pragma unroll
            for (int i = 0; i < 10; i++) h[i] = nh[i];
        }
#pragma unroll
        for (int i = 0; i < 10; i++) Dl[m][i] = h[i];
    }

    // ---- phase B1: A^64 via 6 squarings ----
    if (tid < 100) P[tid] = Wih[(tid / 10) * 20 + 10 + (tid % 10)];
    __syncthreads();
    for (int it = 0; it < 6; it++) {
        if (tid < 100) {
            int i = tid / 10, j = tid % 10;
            float s = 0.f;
#pragma unroll
            for (int k = 0; k < 10; k++) s += P[i * 10 + k] * P[k * 10 + j];
            Q[tid] = s;
        }
        __syncthreads();
        if (tid < 100) P[tid] = Q[tid];
        __syncthreads();
    }

    // ---- phase B2: chunk-boundary scan (lanes 0..9, wave-lockstep) ----
    if (tid < 10) Hl[tid] = 0.f;
    __syncthreads();
    if (tid < 10) {
        int i = tid;
        float a64[10];
#pragma unroll
        for (int j = 0; j < 10; j++) a64[j] = P[i * 10 + j];
        float hc = 0.f;
        for (int m = 0; m < NCH; m++) {
            Hst[m][i] = hc;
            float s = Dl[m][i];
#pragma unroll
            for (int j = 0; j < 10; j++) s += a64[j] * Hl[j];
            Hl[i] = s;
            hc = s;
        }
    }
    __syncthreads();

    // ---- phase C: re-run with true starts; CmbT[10+i][m*64+k] = h_t ----
    {
        int m = tid;
        float h[10];
#pragma unroll
        for (int i = 0; i < 10; i++) h[i] = Hst[m][i];
        const float* cvb = ws + OFF_CVEC;
        for (int k = 0; k < L; k++) {
            int tg = m * 64 + k;
#pragma unroll
            for (int i = 0; i < 10; i++) ws[OFF_CMB + (10 + i) * SEQ + tg] = h[i];
            const float* c = cvb + (k * NCH + m) * 10;
            float nh[10];
#pragma unroll
            for (int i = 0; i < 10; i++) {
                float s = c[i];
#pragma unroll
                for (int j = 0; j < 10; j++) s += Ar[i][j] * h[j];
                nh[i] = s;
            }
#pragma unroll
            for (int i = 0; i < 10; i++) h[i] = nh[i];
        }
    }
}

// ---------------------------------------------------------------------------
// K4: fused logits + argmax. W slice (512 v, 40 KB) in LDS (ds_read_b128);
// combined c read via wave-uniform SCALAR loads (readfirstlane'd base ->
// s_load, values feed v_fma as the SGPR operand) -- no cvv VGPRs, no VMEM.
// Grid: 2000 = 250 v-slices x 8 t-quarters (1024 t). Block: 4 waves; per
// 64-t pass each wave owns 16 t, sweeps 512 v as 2 subs of acc[16][4].
// Live VGPRs ~118 < 128 -> no spill at the compiler's 128-reg allocation.
// Argmax merged via packed u64 atomicMax (exact jnp.argmax semantics).
// ---------------------------------------------------------------------------
__global__ __launch_bounds__(256, 2)
void k_logits(const float* __restrict__ ws, const float* __restrict__ bio,
              unsigned long long* __restrict__ amax) {
    __shared__ float Wl[20 * 512];        // 40 KB

    int tid = threadIdx.x;
    int vt  = tid & 63;
    int tg  = tid >> 6;

    int b     = blockIdx.x;
    int sl    = b % 250;                  // v-slice (512 v)
    int tq    = b / 250;                  // t-quarter (1024 t)
    int tbase = tq * 1024;

    const float4* WT4 = (const float4*)(ws + OFF_WT);
    const float4* B4  = (const float4*)bio;
    float4* Wl4 = (float4*)Wl;

    // ---- stage W slice: 2560 float4, 10 per thread ----
#pragma unroll
    for (int r = 0; r < 10; r++) {
        int F = tid + 256 * r;            // = k*128 + j
        int k = F >> 7, j = F & 127;
        Wl4[F] = WT4[k * 32000 + sl * 128 + j];
    }
    __syncthreads();

    float4 b4a = B4[sl * 128 + vt];
    float4 b4b = B4[sl * 128 + 64 + vt];
    int v0a = sl * 512 + 4 * vt;
    int v0b = v0a + 256;

    const float* __restrict__ cmb = ws + OFF_CMB;

    for (int p = 0; p < 16; p++) {
        int tb  = tbase + p * 64 + tg * 16;            // this wave's 16 t
        int tbu = __builtin_amdgcn_readfirstlane(tb);  // provably wave-uniform

        float best[16];
        int   bidx[16];
#pragma unroll
        for (int t = 0; t < 16; t++) { best[t] = -1e30f; bidx[t] = 0; }

#pragma unroll
        for (int sub = 0; sub < 2; sub++) {
            float4 b4 = (sub == 0) ? b4a : b4b;
            int    v0 = (sub == 0) ? v0a : v0b;

            float acc[16][4];
#pragma unroll
            for (int t = 0; t < 16; t++) {
                acc[t][0] = b4.x; acc[t][1] = b4.y; acc[t][2] = b4.z; acc[t][3] = b4.w;
            }
#pragma unroll
            for (int k = 0; k < 20; k++) {
                float4 w4 = Wl4[k * 128 + sub * 64 + vt];
                const float* cc = cmb + k * SEQ + tbu;   // uniform -> s_load
#pragma unroll
                for (int t = 0; t < 16; t++) {
                    float cv = cc[t];                    // SGPR operand
                    acc[t][0] += cv * w4.x;
                    acc[t][1] += cv * w4.y;
                    acc[t][2] += cv * w4.z;
                    acc[t][3] += cv * w4.w;
                }
            }
#pragma unroll
            for (int t = 0; t < 16; t++) {
#pragma unroll
                for (int j = 0; j < 4; j++) {
                    if (acc[t][j] > best[t]) { best[t] = acc[t][j]; bidx[t] = v0 + j; }
                }
            }
        }

        // cross-lane argmax (64 lanes hold disjoint v; ties -> lower idx)
#pragma unroll
        for (int t = 0; t < 16; t++) {
            float bv = best[t]; int bi = bidx[t];
            for (int off = 32; off > 0; off >>= 1) {
                float ov = __shfl_down(bv, off);
                int   oi = __shfl_down(bi, off);
                if (ov > bv || (ov == bv && oi < bi)) { bv = ov; bi = oi; }
            }
            if (vt == 0) {
                unsigned int u = __float_as_uint(bv);
                unsigned int key = (u & 0x80000000u) ? ~u : (u | 0x80000000u);
                unsigned long long packed =
                    ((unsigned long long)key << 32) | (unsigned int)(VOCAB - bi);
                atomicMax(&amax[tbu + t], packed);
            }
        }
    }
}

// ---------------------------------------------------------------------------
// K5: unpack argmax -> float index
// ---------------------------------------------------------------------------
__global__ void k_out(const unsigned long long* __restrict__ amax,
                      float* __restrict__ out) {
    int t = blockIdx.x * blockDim.x + threadIdx.x;
    if (t >= SEQ) return;
    unsigned long long p = amax[t];
    int idx = VOCAB - (int)(p & 0xFFFFFFFFu);
    out[t] = (float)idx;
}

// ---------------------------------------------------------------------------
extern "C" void kernel_launch(void* const* d_in, const int* in_sizes, int n_in,
                              void* d_out, int out_size, void* d_ws, size_t ws_size,
                              hipStream_t stream) {
    (void)in_sizes; (void)n_in; (void)out_size; (void)ws_size;
    const int*   ix  = (const int*)d_in[0];
    const float* emb = (const float*)d_in[1];
    const float* Wih = (const float*)d_in[2];
    const float* bih = (const float*)d_in[3];
    const float* Wio = (const float*)d_in[4];
    const float* bio = (const float*)d_in[5];
    float* out = (float*)d_out;
    float* ws  = (float*)d_ws;
    unsigned long long* amax = (unsigned long long*)(ws + OFF_AMAX);

    hipLaunchKernelGGL(k_embed,     dim3(SEQ / 256), dim3(256), 0, stream, ix, emb, Wih, bih, ws);
    hipLaunchKernelGGL(k_transpose, dim3(VOCAB / 256), dim3(256), 0, stream, Wio, ws);
    hipLaunchKernelGGL(k_scan,      dim3(1), dim3(128), 0, stream, Wih, ws);
    hipLaunchKernelGGL(k_logits,    dim3(2000), dim3(256), 0, stream, ws, bio, amax);
    hipLaunchKernelGGL(k_out,       dim3(SEQ / 256), dim3(256), 0, stream, amax, out);
}

// Round 6
// 947.054 us; speedup vs baseline: 18.9693x; 2.2545x over previous
//
#include <hip/hip_runtime.h>

#define SEQ   8192
#define VOCAB 128000
#define L     64
#define NCH   128   // SEQ / L

// ws layout (float offsets)
#define OFF_CMB  0          // CmbT[k][t] : [20][8192] combined, k-major (640 KB)
#define OFF_CVEC 163840     // cvecT[k][m][i] : [64][128][10]
#define OFF_AMAX 245760     // amax[t] : 8192 x u64 packed (key<<32 | VOCAB-idx)
// total = 262,144 floats = 1.05 MB

// ---------------------------------------------------------------------------
// K1: gather embeddings -> CmbT rows 0..9; cvec_t = W_i2h[:,:10]*w_t + b_i2h;
//     zero the atomic-argmax array.
// ---------------------------------------------------------------------------
__global__ void k_embed(const int* __restrict__ ix, const float* __restrict__ emb,
                        const float* __restrict__ Wih, const float* __restrict__ bih,
                        float* __restrict__ ws) {
    int t = blockIdx.x * blockDim.x + threadIdx.x;
    if (t >= SEQ) return;

    ((unsigned long long*)(ws + OFF_AMAX))[t] = 0ULL;   // zero packed argmax

    int id = ix[t];
    float w[10];
    const float2* ep = (const float2*)(emb + (long long)id * 10);
#pragma unroll
    for (int j = 0; j < 5; j++) ((float2*)w)[j] = ep[j];

    // CmbT[j][t] = w[j]  (coalesced: consecutive t -> consecutive addr)
#pragma unroll
    for (int j = 0; j < 10; j++) ws[OFF_CMB + j * SEQ + t] = w[j];

    int m = t >> 6, k = t & 63;
    float* cv = ws + OFF_CVEC + (k * NCH + m) * 10;
#pragma unroll
    for (int i = 0; i < 10; i++) {
        float s = bih[i];
#pragma unroll
        for (int j = 0; j < 10; j++) s += Wih[i * 20 + j] * w[j];
        cv[i] = s;
    }
}

// ---------------------------------------------------------------------------
// K3: blocked scan of h_{t+1} = A h_t + c_t; writes h_t into CmbT rows 10..19
// ---------------------------------------------------------------------------
__global__ void k_scan(const float* __restrict__ Wih, float* __restrict__ ws) {
    __shared__ float P[100], Q[100];
    __shared__ float Dl[NCH][10];
    __shared__ float Hst[NCH][10];
    __shared__ float Hl[10];
    int tid = threadIdx.x;

    float Ar[10][10];
#pragma unroll
    for (int i = 0; i < 10; i++)
#pragma unroll
        for (int j = 0; j < 10; j++) Ar[i][j] = Wih[i * 20 + 10 + j];

    // ---- phase A: each thread = one chunk, from zero state ----
    {
        int m = tid;
        float h[10];
#pragma unroll
        for (int i = 0; i < 10; i++) h[i] = 0.f;
        const float* cvb = ws + OFF_CVEC;
        for (int k = 0; k < L; k++) {
            const float* c = cvb + (k * NCH + m) * 10;
            float nh[10];
#pragma unroll
            for (int i = 0; i < 10; i++) {
                float s = c[i];
#pragma unroll
                for (int j = 0; j < 10; j++) s += Ar[i][j] * h[j];
                nh[i] = s;
            }
#pragma unroll
            for (int i = 0; i < 10; i++) h[i] = nh[i];
        }
#pragma unroll
        for (int i = 0; i < 10; i++) Dl[m][i] = h[i];
    }

    // ---- phase B1: A^64 via 6 squarings ----
    if (tid < 100) P[tid] = Wih[(tid / 10) * 20 + 10 + (tid % 10)];
    __syncthreads();
    for (int it = 0; it < 6; it++) {
        if (tid < 100) {
            int i = tid / 10, j = tid % 10;
            float s = 0.f;
#pragma unroll
            for (int k = 0; k < 10; k++) s += P[i * 10 + k] * P[k * 10 + j];
            Q[tid] = s;
        }
        __syncthreads();
        if (tid < 100) P[tid] = Q[tid];
        __syncthreads();
    }

    // ---- phase B2: chunk-boundary scan (lanes 0..9, wave-lockstep) ----
    if (tid < 10) Hl[tid] = 0.f;
    __syncthreads();
    if (tid < 10) {
        int i = tid;
        float a64[10];
#pragma unroll
        for (int j = 0; j < 10; j++) a64[j] = P[i * 10 + j];
        float hc = 0.f;
        for (int m = 0; m < NCH; m++) {
            Hst[m][i] = hc;
            float s = Dl[m][i];
#pragma unroll
            for (int j = 0; j < 10; j++) s += a64[j] * Hl[j];
            Hl[i] = s;
            hc = s;
        }
    }
    __syncthreads();

    // ---- phase C: re-run with true starts; CmbT[10+i][m*64+k] = h_t ----
    {
        int m = tid;
        float h[10];
#pragma unroll
        for (int i = 0; i < 10; i++) h[i] = Hst[m][i];
        const float* cvb = ws + OFF_CVEC;
        for (int k = 0; k < L; k++) {
            int tg = m * 64 + k;
#pragma unroll
            for (int i = 0; i < 10; i++) ws[OFF_CMB + (10 + i) * SEQ + tg] = h[i];
            const float* c = cvb + (k * NCH + m) * 10;
            float nh[10];
#pragma unroll
            for (int i = 0; i < 10; i++) {
                float s = c[i];
#pragma unroll
                for (int j = 0; j < 10; j++) s += Ar[i][j] * h[j];
                nh[i] = s;
            }
#pragma unroll
            for (int i = 0; i < 10; i++) h[i] = nh[i];
        }
    }
}

// ---------------------------------------------------------------------------
// K4: fused logits + argmax, lane-per-timestep.
// Grid: 8000 = 250 v-slices (512 v) x 32 t-tiles (256 t). Block: 4 waves;
// lane owns t = tile*256 + wave*64 + lane, with c[20] in VGPRs. v is
// wave-uniform: W rows (original [v][20] layout) and biases arrive via
// SCALAR loads (SGPR ping-pong double-buffer, SMEM pipe). 4 independent
// FMA chains (v-pair x k-split). Argmax is purely per-lane (ascending v,
// strict >); one packed-u64 atomicMax per lane at the end. No LDS, no
// shuffles, ~35 live VGPRs -> no spill.
// ---------------------------------------------------------------------------
__global__ __launch_bounds__(256, 4)
void k_logits(const float* __restrict__ ws, const float* __restrict__ Wio,
              const float* __restrict__ bio, unsigned long long* __restrict__ amax) {
    int tid  = threadIdx.x;
    int lane = tid & 63;
    int wv   = tid >> 6;

    int sl = __builtin_amdgcn_readfirstlane(blockIdx.x % 250);   // v-slice
    int tt = __builtin_amdgcn_readfirstlane(blockIdx.x / 250);   // t-tile
    int t  = tt * 256 + wv * 64 + lane;

    // per-lane combined vector (coalesced loads: consecutive lanes -> consecutive t)
    float c[20];
    const float* cmb = ws + OFF_CMB;
#pragma unroll
    for (int k = 0; k < 20; k++) c[k] = cmb[k * SEQ + t];

    int v0 = sl * 512;
    float best = -3.4e38f;
    int   bidx = 0;

    float wa[40], wb[40];
    float ba0, ba1, bb0, bb1;

    // prefetch pair 0 into A
    {
        const float* Wr = Wio + (long long)v0 * 20;
#pragma unroll
        for (int j = 0; j < 40; j++) wa[j] = Wr[j];
        ba0 = bio[v0]; ba1 = bio[v0 + 1];
    }

    for (int i = 0; i < 256; i += 2) {
        // prefetch pair i+1 into B
        {
            const float* Wr = Wio + (long long)(v0 + 2 * (i + 1)) * 20;
#pragma unroll
            for (int j = 0; j < 40; j++) wb[j] = Wr[j];
            bb0 = bio[v0 + 2 * (i + 1)]; bb1 = bio[v0 + 2 * (i + 1) + 1];
        }
        // compute pair i from A
        {
            float a0 = 0.f, a1 = 0.f, a2 = 0.f, a3 = 0.f;
#pragma unroll
            for (int k = 0; k < 10; k++) {
                a0 += wa[k]      * c[k];
                a1 += wa[10 + k] * c[10 + k];
                a2 += wa[20 + k] * c[k];
                a3 += wa[30 + k] * c[10 + k];
            }
            float l0 = ba0 + a0 + a1;
            float l1 = ba1 + a2 + a3;
            int v = v0 + 2 * i;
            if (l0 > best) { best = l0; bidx = v; }
            if (l1 > best) { best = l1; bidx = v + 1; }
        }
        // prefetch pair i+2 into A (wrap to 0 on last iter: harmless reread)
        {
            int inx = (i + 2 < 256) ? (i + 2) : 0;
            const float* Wr = Wio + (long long)(v0 + 2 * inx) * 20;
#pragma unroll
            for (int j = 0; j < 40; j++) wa[j] = Wr[j];
            ba0 = bio[v0 + 2 * inx]; ba1 = bio[v0 + 2 * inx + 1];
        }
        // compute pair i+1 from B
        {
            float a0 = 0.f, a1 = 0.f, a2 = 0.f, a3 = 0.f;
#pragma unroll
            for (int k = 0; k < 10; k++) {
                a0 += wb[k]      * c[k];
                a1 += wb[10 + k] * c[10 + k];
                a2 += wb[20 + k] * c[k];
                a3 += wb[30 + k] * c[10 + k];
            }
            float l0 = bb0 + a0 + a1;
            float l1 = bb1 + a2 + a3;
            int v = v0 + 2 * (i + 1);
            if (l0 > best) { best = l0; bidx = v; }
            if (l1 > best) { best = l1; bidx = v + 1; }
        }
    }

    // per-lane global merge (exact jnp.argmax semantics: max value, lowest idx)
    unsigned int u = __float_as_uint(best);
    unsigned int key = (u & 0x80000000u) ? ~u : (u | 0x80000000u);
    unsigned long long packed =
        ((unsigned long long)key << 32) | (unsigned int)(VOCAB - bidx);
    atomicMax(&amax[t], packed);
}

// ---------------------------------------------------------------------------
// K5: unpack argmax -> float index
// ---------------------------------------------------------------------------
__global__ void k_out(const unsigned long long* __restrict__ amax,
                      float* __restrict__ out) {
    int t = blockIdx.x * blockDim.x + threadIdx.x;
    if (t >= SEQ) return;
    unsigned long long p = amax[t];
    int idx = VOCAB - (int)(p & 0xFFFFFFFFu);
    out[t] = (float)idx;
}

// ---------------------------------------------------------------------------
extern "C" void kernel_launch(void* const* d_in, const int* in_sizes, int n_in,
                              void* d_out, int out_size, void* d_ws, size_t ws_size,
                              hipStream_t stream) {
    (void)in_sizes; (void)n_in; (void)out_size; (void)ws_size;
    const int*   ix  = (const int*)d_in[0];
    const float* emb = (const float*)d_in[1];
    const float* Wih = (const float*)d_in[2];
    const float* bih = (const float*)d_in[3];
    const float* Wio = (const float*)d_in[4];
    const float* bio = (const float*)d_in[5];
    float* out = (float*)d_out;
    float* ws  = (float*)d_ws;
    unsigned long long* amax = (unsigned long long*)(ws + OFF_AMAX);

    hipLaunchKernelGGL(k_embed,  dim3(SEQ / 256), dim3(256), 0, stream, ix, emb, Wih, bih, ws);
    hipLaunchKernelGGL(k_scan,   dim3(1), dim3(128), 0, stream, Wih, ws);
    hipLaunchKernelGGL(k_logits, dim3(8000), dim3(256), 0, stream, ws, Wio, bio, amax);
    hipLaunchKernelGGL(k_out,    dim3(SEQ / 256), dim3(256), 0, stream, amax, out);
}

// Round 7
// 832.521 us; speedup vs baseline: 21.5789x; 1.1376x over previous
//
#include <hip/hip_runtime.h>

#define SEQ   8192
#define VOCAB 128000
#define L     64
#define NCH   128   // SEQ / L
#define VSL   256   // vocab rows per slice (LDS-staged)

// ws layout (float offsets)
#define OFF_CMB  0          // CmbT[k][t] : [20][8192] combined, k-major (640 KB)
#define OFF_CVEC 163840     // cvecT[k][m][i] : [64][128][10]
#define OFF_AMAX 245760     // amax[t] : 8192 x u64 packed (key<<32 | VOCAB-idx)
// total = 262,144 floats = 1.05 MB

// ---------------------------------------------------------------------------
// K1: gather embeddings -> CmbT rows 0..9; cvec_t = W_i2h[:,:10]*w_t + b_i2h;
//     zero the atomic-argmax array.
// ---------------------------------------------------------------------------
__global__ void k_embed(const int* __restrict__ ix, const float* __restrict__ emb,
                        const float* __restrict__ Wih, const float* __restrict__ bih,
                        float* __restrict__ ws) {
    int t = blockIdx.x * blockDim.x + threadIdx.x;
    if (t >= SEQ) return;

    ((unsigned long long*)(ws + OFF_AMAX))[t] = 0ULL;   // zero packed argmax

    int id = ix[t];
    float w[10];
    const float2* ep = (const float2*)(emb + (long long)id * 10);
#pragma unroll
    for (int j = 0; j < 5; j++) ((float2*)w)[j] = ep[j];

    // CmbT[j][t] = w[j]  (coalesced: consecutive t -> consecutive addr)
#pragma unroll
    for (int j = 0; j < 10; j++) ws[OFF_CMB + j * SEQ + t] = w[j];

    int m = t >> 6, k = t & 63;
    float* cv = ws + OFF_CVEC + (k * NCH + m) * 10;
#pragma unroll
    for (int i = 0; i < 10; i++) {
        float s = bih[i];
#pragma unroll
        for (int j = 0; j < 10; j++) s += Wih[i * 20 + j] * w[j];
        cv[i] = s;
    }
}

// ---------------------------------------------------------------------------
// K3: blocked scan of h_{t+1} = A h_t + c_t; writes h_t into CmbT rows 10..19
// ---------------------------------------------------------------------------
__global__ void k_scan(const float* __restrict__ Wih, float* __restrict__ ws) {
    __shared__ float P[100], Q[100];
    __shared__ float Dl[NCH][10];
    __shared__ float Hst[NCH][10];
    __shared__ float Hl[10];
    int tid = threadIdx.x;

    float Ar[10][10];
#pragma unroll
    for (int i = 0; i < 10; i++)
#pragma unroll
        for (int j = 0; j < 10; j++) Ar[i][j] = Wih[i * 20 + 10 + j];

    // ---- phase A: each thread = one chunk, from zero state ----
    {
        int m = tid;
        float h[10];
#pragma unroll
        for (int i = 0; i < 10; i++) h[i] = 0.f;
        const float* cvb = ws + OFF_CVEC;
        for (int k = 0; k < L; k++) {
            const float* c = cvb + (k * NCH + m) * 10;
            float nh[10];
#pragma unroll
            for (int i = 0; i < 10; i++) {
                float s = c[i];
#pragma unroll
                for (int j = 0; j < 10; j++) s += Ar[i][j] * h[j];
                nh[i] = s;
            }
#pragma unroll
            for (int i = 0; i < 10; i++) h[i] = nh[i];
        }
#pragma unroll
        for (int i = 0; i < 10; i++) Dl[m][i] = h[i];
    }

    // ---- phase B1: A^64 via 6 squarings ----
    if (tid < 100) P[tid] = Wih[(tid / 10) * 20 + 10 + (tid % 10)];
    __syncthreads();
    for (int it = 0; it < 6; it++) {
        if (tid < 100) {
            int i = tid / 10, j = tid % 10;
            float s = 0.f;
#pragma unroll
            for (int k = 0; k < 10; k++) s += P[i * 10 + k] * P[k * 10 + j];
            Q[tid] = s;
        }
        __syncthreads();
        if (tid < 100) P[tid] = Q[tid];
        __syncthreads();
    }

    // ---- phase B2: chunk-boundary scan (lanes 0..9, wave-lockstep) ----
    if (tid < 10) Hl[tid] = 0.f;
    __syncthreads();
    if (tid < 10) {
        int i = tid;
        float a64[10];
#pragma unroll
        for (int j = 0; j < 10; j++) a64[j] = P[i * 10 + j];
        float hc = 0.f;
        for (int m = 0; m < NCH; m++) {
            Hst[m][i] = hc;
            float s = Dl[m][i];
#pragma unroll
            for (int j = 0; j < 10; j++) s += a64[j] * Hl[j];
            Hl[i] = s;
            hc = s;
        }
    }
    __syncthreads();

    // ---- phase C: re-run with true starts; CmbT[10+i][m*64+k] = h_t ----
    {
        int m = tid;
        float h[10];
#pragma unroll
        for (int i = 0; i < 10; i++) h[i] = Hst[m][i];
        const float* cvb = ws + OFF_CVEC;
        for (int k = 0; k < L; k++) {
            int tg = m * 64 + k;
#pragma unroll
            for (int i = 0; i < 10; i++) ws[OFF_CMB + (10 + i) * SEQ + tg] = h[i];
            const float* c = cvb + (k * NCH + m) * 10;
            float nh[10];
#pragma unroll
            for (int i = 0; i < 10; i++) {
                float s = c[i];
#pragma unroll
                for (int j = 0; j < 10; j++) s += Ar[i][j] * h[j];
                nh[i] = s;
            }
#pragma unroll
            for (int i = 0; i < 10; i++) h[i] = nh[i];
        }
    }
}

// ---------------------------------------------------------------------------
// K4: fused logits + argmax, lane-per-2-timesteps, W slice in LDS.
// Grid: 8000 = 500 v-slices (256 v) x 16 t-tiles (512 t). Block: 256 thr.
// Stage: W slice 20 KB (row-major, coalesced float4, no transpose) + bias
// 1 KB into LDS. Thread owns t0 = tile*512 + tid and t1 = t0 + 256 with
// c0[20], c1[20] in VGPRs. Sweep 256 v rows: per row 5x ds_read_b128 +
// 1x ds_read_b32, wave-uniform address -> LDS broadcast (no conflict,
// in-order lgkmcnt -> pipelineable), 40 FMA. Two-row ping-pong register
// buffer; no barriers in the loop. Argmax purely per-lane (ascending v,
// strict >); 2 packed-u64 atomicMax per thread at the end.
// ---------------------------------------------------------------------------
__global__ __launch_bounds__(256, 4)
void k_logits(const float* __restrict__ ws, const float* __restrict__ Wio,
              const float* __restrict__ bio, unsigned long long* __restrict__ amax) {
    __shared__ float Wl[VSL * 20];   // 20 KB, row-major [v][20]
    __shared__ float Bl[VSL];        // 1 KB

    int tid = threadIdx.x;
    int sl  = blockIdx.x % 500;      // v-slice
    int tt  = blockIdx.x / 500;      // t-tile
    int v0  = sl * VSL;

    // ---- stage W slice: 1280 float4, 5 per thread (contiguous, coalesced) ----
    {
        const float4* Wg = (const float4*)(Wio + (long long)v0 * 20);
        float4* Wl4 = (float4*)Wl;
#pragma unroll
        for (int r = 0; r < 5; r++) Wl4[tid + 256 * r] = Wg[tid + 256 * r];
        if (tid < 64) ((float4*)Bl)[tid] = ((const float4*)(bio + v0))[tid];
    }
    __syncthreads();

    int t0 = tt * 512 + tid;         // this thread's first t (t1 = t0 + 256)

    // per-thread combined vectors (coalesced: consecutive tid -> consecutive t)
    float c0[20], c1[20];
    const float* cmb = ws + OFF_CMB;
#pragma unroll
    for (int k = 0; k < 20; k++) {
        c0[k] = cmb[k * SEQ + t0];
        c1[k] = cmb[k * SEQ + t0 + 256];
    }

    float best0 = -3.4e38f, best1 = -3.4e38f;
    int   bi0 = 0, bi1 = 0;

    float4 wa[5], wb[5];
    float  bba, bbb;

    // prefetch row 0 into A
#pragma unroll
    for (int q = 0; q < 5; q++) wa[q] = ((const float4*)Wl)[q];
    bba = Bl[0];

    for (int r = 0; r < VSL; r += 2) {
        // prefetch row r+1 into B
        {
            const float4* rp = (const float4*)(Wl + (r + 1) * 20);
#pragma unroll
            for (int q = 0; q < 5; q++) wb[q] = rp[q];
            bbb = Bl[r + 1];
        }
        // compute row r from A
        {
            const float* w = (const float*)wa;
            float a0 = bba, a1 = 0.f, a2 = bba, a3 = 0.f;
#pragma unroll
            for (int k = 0; k < 10; k++) {
                a0 += w[k]      * c0[k];
                a1 += w[10 + k] * c0[10 + k];
                a2 += w[k]      * c1[k];
                a3 += w[10 + k] * c1[10 + k];
            }
            float l0 = a0 + a1, l1 = a2 + a3;
            int v = v0 + r;
            if (l0 > best0) { best0 = l0; bi0 = v; }
            if (l1 > best1) { best1 = l1; bi1 = v; }
        }
        // prefetch row r+2 into A (wrap on last iter: harmless reread)
        {
            int rn = (r + 2 < VSL) ? r + 2 : 0;
            const float4* rp = (const float4*)(Wl + rn * 20);
#pragma unroll
            for (int q = 0; q < 5; q++) wa[q] = rp[q];
            bba = Bl[rn];
        }
        // compute row r+1 from B
        {
            const float* w = (const float*)wb;
            float a0 = bbb, a1 = 0.f, a2 = bbb, a3 = 0.f;
#pragma unroll
            for (int k = 0; k < 10; k++) {
                a0 += w[k]      * c0[k];
                a1 += w[10 + k] * c0[10 + k];
                a2 += w[k]      * c1[k];
                a3 += w[10 + k] * c1[10 + k];
            }
            float l0 = a0 + a1, l1 = a2 + a3;
            int v = v0 + r + 1;
            if (l0 > best0) { best0 = l0; bi0 = v; }
            if (l1 > best1) { best1 = l1; bi1 = v; }
        }
    }

    // per-lane global merge (exact jnp.argmax semantics: max value, lowest idx)
    {
        unsigned int u = __float_as_uint(best0);
        unsigned int key = (u & 0x80000000u) ? ~u : (u | 0x80000000u);
        unsigned long long packed =
            ((unsigned long long)key << 32) | (unsigned int)(VOCAB - bi0);
        atomicMax(&amax[t0], packed);
    }
    {
        unsigned int u = __float_as_uint(best1);
        unsigned int key = (u & 0x80000000u) ? ~u : (u | 0x80000000u);
        unsigned long long packed =
            ((unsigned long long)key << 32) | (unsigned int)(VOCAB - bi1);
        atomicMax(&amax[t0 + 256], packed);
    }
}

// ---------------------------------------------------------------------------
// K5: unpack argmax -> float index
// ---------------------------------------------------------------------------
__global__ void k_out(const unsigned long long* __restrict__ amax,
                      float* __restrict__ out) {
    int t = blockIdx.x * blockDim.x + threadIdx.x;
    if (t >= SEQ) return;
    unsigned long long p = amax[t];
    int idx = VOCAB - (int)(p & 0xFFFFFFFFu);
    out[t] = (float)idx;
}

// ---------------------------------------------------------------------------
extern "C" void kernel_launch(void* const* d_in, const int* in_sizes, int n_in,
                              void* d_out, int out_size, void* d_ws, size_t ws_size,
                              hipStream_t stream) {
    (void)in_sizes; (void)n_in; (void)out_size; (void)ws_size;
    const int*   ix  = (const int*)d_in[0];
    const float* emb = (const float*)d_in[1];
    const float* Wih = (const float*)d_in[2];
    const float* bih = (const float*)d_in[3];
    const float* Wio = (const float*)d_in[4];
    const float* bio = (const float*)d_in[5];
    float* out = (float*)d_out;
    float* ws  = (float*)d_ws;
    unsigned long long* amax = (unsigned long long*)(ws + OFF_AMAX);

    hipLaunchKernelGGL(k_embed,  dim3(SEQ / 256), dim3(256), 0, stream, ix, emb, Wih, bih, ws);
    hipLaunchKernelGGL(k_scan,   dim3(1), dim3(128), 0, stream, Wih, ws);
    hipLaunchKernelGGL(k_logits, dim3(8000), dim3(256), 0, stream, ws, Wio, bio, amax);
    hipLaunchKernelGGL(k_out,    dim3(SEQ / 256), dim3(256), 0, stream, amax, out);
}

// Round 8
// 794.423 us; speedup vs baseline: 22.6138x; 1.0480x over previous
//
#include <hip/hip_runtime.h>

#define SEQ   8192
#define VOCAB 128000
#define L     64
#define NCH   128   // SEQ / L
#define VSL   256   // vocab rows per slice (LDS-staged)

// ws layout (float offsets)
#define OFF_CMB  0          // CmbT[k][t] : [20][8192] combined, k-major (640 KB)
#define OFF_CVEC 163840     // cvecT[k][m][i] : [64][128][10]
#define OFF_AMAX 245760     // amax[t] : 8192 x u64 packed (key<<32 | VOCAB-idx)
// total = 262,144 floats = 1.05 MB

// ---------------------------------------------------------------------------
// K1: gather embeddings -> CmbT rows 0..9; cvec_t = W_i2h[:,:10]*w_t + b_i2h;
//     zero the atomic-argmax array.
// ---------------------------------------------------------------------------
__global__ void k_embed(const int* __restrict__ ix, const float* __restrict__ emb,
                        const float* __restrict__ Wih, const float* __restrict__ bih,
                        float* __restrict__ ws) {
    int t = blockIdx.x * blockDim.x + threadIdx.x;
    if (t >= SEQ) return;

    ((unsigned long long*)(ws + OFF_AMAX))[t] = 0ULL;   // zero packed argmax

    int id = ix[t];
    float w[10];
    const float2* ep = (const float2*)(emb + (long long)id * 10);
#pragma unroll
    for (int j = 0; j < 5; j++) ((float2*)w)[j] = ep[j];

    // CmbT[j][t] = w[j]  (coalesced: consecutive t -> consecutive addr)
#pragma unroll
    for (int j = 0; j < 10; j++) ws[OFF_CMB + j * SEQ + t] = w[j];

    int m = t >> 6, k = t & 63;
    float* cv = ws + OFF_CVEC + (k * NCH + m) * 10;
#pragma unroll
    for (int i = 0; i < 10; i++) {
        float s = bih[i];
#pragma unroll
        for (int j = 0; j < 10; j++) s += Wih[i * 20 + j] * w[j];
        cv[i] = s;
    }
}

// ---------------------------------------------------------------------------
// K3: blocked scan of h_{t+1} = A h_t + c_t; writes h_t into CmbT rows 10..19
// ---------------------------------------------------------------------------
__global__ void k_scan(const float* __restrict__ Wih, float* __restrict__ ws) {
    __shared__ float P[100], Q[100];
    __shared__ float Dl[NCH][10];
    __shared__ float Hst[NCH][10];
    __shared__ float Hl[10];
    int tid = threadIdx.x;

    float Ar[10][10];
#pragma unroll
    for (int i = 0; i < 10; i++)
#pragma unroll
        for (int j = 0; j < 10; j++) Ar[i][j] = Wih[i * 20 + 10 + j];

    // ---- phase A: each thread = one chunk, from zero state ----
    {
        int m = tid;
        float h[10];
#pragma unroll
        for (int i = 0; i < 10; i++) h[i] = 0.f;
        const float* cvb = ws + OFF_CVEC;
        for (int k = 0; k < L; k++) {
            const float* c = cvb + (k * NCH + m) * 10;
            float nh[10];
#pragma unroll
            for (int i = 0; i < 10; i++) {
                float s = c[i];
#pragma unroll
                for (int j = 0; j < 10; j++) s += Ar[i][j] * h[j];
                nh[i] = s;
            }
#pragma unroll
            for (int i = 0; i < 10; i++) h[i] = nh[i];
        }
#pragma unroll
        for (int i = 0; i < 10; i++) Dl[m][i] = h[i];
    }

    // ---- phase B1: A^64 via 6 squarings ----
    if (tid < 100) P[tid] = Wih[(tid / 10) * 20 + 10 + (tid % 10)];
    __syncthreads();
    for (int it = 0; it < 6; it++) {
        if (tid < 100) {
            int i = tid / 10, j = tid % 10;
            float s = 0.f;
#pragma unroll
            for (int k = 0; k < 10; k++) s += P[i * 10 + k] * P[k * 10 + j];
            Q[tid] = s;
        }
        __syncthreads();
        if (tid < 100) P[tid] = Q[tid];
        __syncthreads();
    }

    // ---- phase B2: chunk-boundary scan (lanes 0..9, wave-lockstep) ----
    if (tid < 10) Hl[tid] = 0.f;
    __syncthreads();
    if (tid < 10) {
        int i = tid;
        float a64[10];
#pragma unroll
        for (int j = 0; j < 10; j++) a64[j] = P[i * 10 + j];
        float hc = 0.f;
        for (int m = 0; m < NCH; m++) {
            Hst[m][i] = hc;
            float s = Dl[m][i];
#pragma unroll
            for (int j = 0; j < 10; j++) s += a64[j] * Hl[j];
            Hl[i] = s;
            hc = s;
        }
    }
    __syncthreads();

    // ---- phase C: re-run with true starts; CmbT[10+i][m*64+k] = h_t ----
    {
        int m = tid;
        float h[10];
#pragma unroll
        for (int i = 0; i < 10; i++) h[i] = Hst[m][i];
        const float* cvb = ws + OFF_CVEC;
        for (int k = 0; k < L; k++) {
            int tg = m * 64 + k;
#pragma unroll
            for (int i = 0; i < 10; i++) ws[OFF_CMB + (10 + i) * SEQ + tg] = h[i];
            const float* c = cvb + (k * NCH + m) * 10;
            float nh[10];
#pragma unroll
            for (int i = 0; i < 10; i++) {
                float s = c[i];
#pragma unroll
                for (int j = 0; j < 10; j++) s += Ar[i][j] * h[j];
                nh[i] = s;
            }
#pragma unroll
            for (int i = 0; i < 10; i++) h[i] = nh[i];
        }
    }
}

// ---------------------------------------------------------------------------
// K4: fused logits + argmax, lane-per-2-timesteps, W slice in LDS.
// Identical structure to Round 7. The one change: amdgpu_waves_per_eu(2,4)
// pins the allocator's occupancy target to <=4 waves/EU so the ~90-reg live
// set (c0[20]+c1[20]+W ping-pong) gets REAL VGPRs instead of AGPR shuttling
// (R7: VGPR_Count=36 < 40 live c-values -> v_accvgpr_read per FMA operand,
// ~2x VALU issue bloat).
// ---------------------------------------------------------------------------
__global__ __launch_bounds__(256)
__attribute__((amdgpu_waves_per_eu(2, 4)))
void k_logits(const float* __restrict__ ws, const float* __restrict__ Wio,
              const float* __restrict__ bio, unsigned long long* __restrict__ amax) {
    __shared__ float Wl[VSL * 20];   // 20 KB, row-major [v][20]
    __shared__ float Bl[VSL];        // 1 KB

    int tid = threadIdx.x;
    int sl  = blockIdx.x % 500;      // v-slice
    int tt  = blockIdx.x / 500;      // t-tile
    int v0  = sl * VSL;

    // ---- stage W slice: 1280 float4, 5 per thread (contiguous, coalesced) ----
    {
        const float4* Wg = (const float4*)(Wio + (long long)v0 * 20);
        float4* Wl4 = (float4*)Wl;
#pragma unroll
        for (int r = 0; r < 5; r++) Wl4[tid + 256 * r] = Wg[tid + 256 * r];
        if (tid < 64) ((float4*)Bl)[tid] = ((const float4*)(bio + v0))[tid];
    }
    __syncthreads();

    int t0 = tt * 512 + tid;         // this thread's first t (t1 = t0 + 256)

    // per-thread combined vectors (coalesced: consecutive tid -> consecutive t)
    float c0[20], c1[20];
    const float* cmb = ws + OFF_CMB;
#pragma unroll
    for (int k = 0; k < 20; k++) {
        c0[k] = cmb[k * SEQ + t0];
        c1[k] = cmb[k * SEQ + t0 + 256];
    }

    float best0 = -3.4e38f, best1 = -3.4e38f;
    int   bi0 = 0, bi1 = 0;

    float4 wa[5], wb[5];
    float  bba, bbb;

    // prefetch row 0 into A
#pragma unroll
    for (int q = 0; q < 5; q++) wa[q] = ((const float4*)Wl)[q];
    bba = Bl[0];

    for (int r = 0; r < VSL; r += 2) {
        // prefetch row r+1 into B
        {
            const float4* rp = (const float4*)(Wl + (r + 1) * 20);
#pragma unroll
            for (int q = 0; q < 5; q++) wb[q] = rp[q];
            bbb = Bl[r + 1];
        }
        // compute row r from A
        {
            const float* w = (const float*)wa;
            float a0 = bba, a1 = 0.f, a2 = bba, a3 = 0.f;
#pragma unroll
            for (int k = 0; k < 10; k++) {
                a0 += w[k]      * c0[k];
                a1 += w[10 + k] * c0[10 + k];
                a2 += w[k]      * c1[k];
                a3 += w[10 + k] * c1[10 + k];
            }
            float l0 = a0 + a1, l1 = a2 + a3;
            int v = v0 + r;
            if (l0 > best0) { best0 = l0; bi0 = v; }
            if (l1 > best1) { best1 = l1; bi1 = v; }
        }
        // prefetch row r+2 into A (wrap on last iter: harmless reread)
        {
            int rn = (r + 2 < VSL) ? r + 2 : 0;
            const float4* rp = (const float4*)(Wl + rn * 20);
#pragma unroll
            for (int q = 0; q < 5; q++) wa[q] = rp[q];
            bba = Bl[rn];
        }
        // compute row r+1 from B
        {
            const float* w = (const float*)wb;
            float a0 = bbb, a1 = 0.f, a2 = bbb, a3 = 0.f;
#pragma unroll
            for (int k = 0; k < 10; k++) {
                a0 += w[k]      * c0[k];
                a1 += w[10 + k] * c0[10 + k];
                a2 += w[k]      * c1[k];
                a3 += w[10 + k] * c1[10 + k];
            }
            float l0 = a0 + a1, l1 = a2 + a3;
            int v = v0 + r + 1;
            if (l0 > best0) { best0 = l0; bi0 = v; }
            if (l1 > best1) { best1 = l1; bi1 = v; }
        }
    }

    // per-lane global merge (exact jnp.argmax semantics: max value, lowest idx)
    {
        unsigned int u = __float_as_uint(best0);
        unsigned int key = (u & 0x80000000u) ? ~u : (u | 0x80000000u);
        unsigned long long packed =
            ((unsigned long long)key << 32) | (unsigned int)(VOCAB - bi0);
        atomicMax(&amax[t0], packed);
    }
    {
        unsigned int u = __float_as_uint(best1);
        unsigned int key = (u & 0x80000000u) ? ~u : (u | 0x80000000u);
        unsigned long long packed =
            ((unsigned long long)key << 32) | (unsigned int)(VOCAB - bi1);
        atomicMax(&amax[t0 + 256], packed);
    }
}

// ---------------------------------------------------------------------------
// K5: unpack argmax -> float index
// ---------------------------------------------------------------------------
__global__ void k_out(const unsigned long long* __restrict__ amax,
                      float* __restrict__ out) {
    int t = blockIdx.x * blockDim.x + threadIdx.x;
    if (t >= SEQ) return;
    unsigned long long p = amax[t];
    int idx = VOCAB - (int)(p & 0xFFFFFFFFu);
    out[t] = (float)idx;
}

// ---------------------------------------------------------------------------
extern "C" void kernel_launch(void* const* d_in, const int* in_sizes, int n_in,
                              void* d_out, int out_size, void* d_ws, size_t ws_size,
                              hipStream_t stream) {
    (void)in_sizes; (void)n_in; (void)out_size; (void)ws_size;
    const int*   ix  = (const int*)d_in[0];
    const float* emb = (const float*)d_in[1];
    const float* Wih = (const float*)d_in[2];
    const float* bih = (const float*)d_in[3];
    const float* Wio = (const float*)d_in[4];
    const float* bio = (const float*)d_in[5];
    float* out = (float*)d_out;
    float* ws  = (float*)d_ws;
    unsigned long long* amax = (unsigned long long*)(ws + OFF_AMAX);

    hipLaunchKernelGGL(k_embed,  dim3(SEQ / 256), dim3(256), 0, stream, ix, emb, Wih, bih, ws);
    hipLaunchKernelGGL(k_scan,   dim3(1), dim3(128), 0, stream, Wih, ws);
    hipLaunchKernelGGL(k_logits, dim3(8000), dim3(256), 0, stream, ws, Wio, bio, amax);
    hipLaunchKernelGGL(k_out,    dim3(SEQ / 256), dim3(256), 0, stream, amax, out);
}

// Round 9
// 655.275 us; speedup vs baseline: 27.4158x; 1.2123x over previous
//
#include <hip/hip_runtime.h>

#define SEQ   8192
#define VOCAB 128000
#define L     64
#define NCH   128   // SEQ / L
#define VSL   256   // vocab rows per slice (LDS-staged)

// ws layout (float offsets)
#define OFF_CMB  0          // CmbT[k][t] : [20][8192] combined, k-major (640 KB)
#define OFF_CVEC 163840     // cvecT[k][m][i] : [64][128][10]
#define OFF_AMAX 245760     // amax[t] : 8192 x u64 packed (key<<32 | VOCAB-idx)
// total = 262,144 floats = 1.05 MB

// ---------------------------------------------------------------------------
// K1: gather embeddings -> CmbT rows 0..9; cvec_t = W_i2h[:,:10]*w_t + b_i2h;
//     zero the atomic-argmax array.
// ---------------------------------------------------------------------------
__global__ void k_embed(const int* __restrict__ ix, const float* __restrict__ emb,
                        const float* __restrict__ Wih, const float* __restrict__ bih,
                        float* __restrict__ ws) {
    int t = blockIdx.x * blockDim.x + threadIdx.x;
    if (t >= SEQ) return;

    ((unsigned long long*)(ws + OFF_AMAX))[t] = 0ULL;   // zero packed argmax

    int id = ix[t];
    float w[10];
    const float2* ep = (const float2*)(emb + (long long)id * 10);
#pragma unroll
    for (int j = 0; j < 5; j++) ((float2*)w)[j] = ep[j];

    // CmbT[j][t] = w[j]  (coalesced: consecutive t -> consecutive addr)
#pragma unroll
    for (int j = 0; j < 10; j++) ws[OFF_CMB + j * SEQ + t] = w[j];

    int m = t >> 6, k = t & 63;
    float* cv = ws + OFF_CVEC + (k * NCH + m) * 10;
#pragma unroll
    for (int i = 0; i < 10; i++) {
        float s = bih[i];
#pragma unroll
        for (int j = 0; j < 10; j++) s += Wih[i * 20 + j] * w[j];
        cv[i] = s;
    }
}

// ---------------------------------------------------------------------------
// K3: blocked scan of h_{t+1} = A h_t + c_t; writes h_t into CmbT rows 10..19
// ---------------------------------------------------------------------------
__global__ void k_scan(const float* __restrict__ Wih, float* __restrict__ ws) {
    __shared__ float P[100], Q[100];
    __shared__ float Dl[NCH][10];
    __shared__ float Hst[NCH][10];
    __shared__ float Hl[10];
    int tid = threadIdx.x;

    float Ar[10][10];
#pragma unroll
    for (int i = 0; i < 10; i++)
#pragma unroll
        for (int j = 0; j < 10; j++) Ar[i][j] = Wih[i * 20 + 10 + j];

    // ---- phase A: each thread = one chunk, from zero state ----
    {
        int m = tid;
        float h[10];
#pragma unroll
        for (int i = 0; i < 10; i++) h[i] = 0.f;
        const float* cvb = ws + OFF_CVEC;
        for (int k = 0; k < L; k++) {
            const float* c = cvb + (k * NCH + m) * 10;
            float nh[10];
#pragma unroll
            for (int i = 0; i < 10; i++) {
                float s = c[i];
#pragma unroll
                for (int j = 0; j < 10; j++) s += Ar[i][j] * h[j];
                nh[i] = s;
            }
#pragma unroll
            for (int i = 0; i < 10; i++) h[i] = nh[i];
        }
#pragma unroll
        for (int i = 0; i < 10; i++) Dl[m][i] = h[i];
    }

    // ---- phase B1: A^64 via 6 squarings ----
    if (tid < 100) P[tid] = Wih[(tid / 10) * 20 + 10 + (tid % 10)];
    __syncthreads();
    for (int it = 0; it < 6; it++) {
        if (tid < 100) {
            int i = tid / 10, j = tid % 10;
            float s = 0.f;
#pragma unroll
            for (int k = 0; k < 10; k++) s += P[i * 10 + k] * P[k * 10 + j];
            Q[tid] = s;
        }
        __syncthreads();
        if (tid < 100) P[tid] = Q[tid];
        __syncthreads();
    }

    // ---- phase B2: chunk-boundary scan (lanes 0..9, wave-lockstep) ----
    if (tid < 10) Hl[tid] = 0.f;
    __syncthreads();
    if (tid < 10) {
        int i = tid;
        float a64[10];
#pragma unroll
        for (int j = 0; j < 10; j++) a64[j] = P[i * 10 + j];
        float hc = 0.f;
        for (int m = 0; m < NCH; m++) {
            Hst[m][i] = hc;
            float s = Dl[m][i];
#pragma unroll
            for (int j = 0; j < 10; j++) s += a64[j] * Hl[j];
            Hl[i] = s;
            hc = s;
        }
    }
    __syncthreads();

    // ---- phase C: re-run with true starts; CmbT[10+i][m*64+k] = h_t ----
    {
        int m = tid;
        float h[10];
#pragma unroll
        for (int i = 0; i < 10; i++) h[i] = Hst[m][i];
        const float* cvb = ws + OFF_CVEC;
        for (int k = 0; k < L; k++) {
            int tg = m * 64 + k;
#pragma unroll
            for (int i = 0; i < 10; i++) ws[OFF_CMB + (10 + i) * SEQ + tg] = h[i];
            const float* c = cvb + (k * NCH + m) * 10;
            float nh[10];
#pragma unroll
            for (int i = 0; i < 10; i++) {
                float s = c[i];
#pragma unroll
                for (int j = 0; j < 10; j++) s += Ar[i][j] * h[j];
                nh[i] = s;
            }
#pragma unroll
            for (int i = 0; i < 10; i++) h[i] = nh[i];
        }
    }
}

// ---------------------------------------------------------------------------
// K4: fused logits + argmax, 4 timesteps per thread, W slice in LDS.
// Grid: 4000 = 500 v-slices (256 v) x 8 t-tiles (1024 t). Block: 256 thr.
// Thread owns t0 = tile*1024 + tid + {0,256,512,768} with c[4][20] in VGPRs.
// Per v-row-pair: 10x ds_read_b128 (W) + 1x ds_read_b64 (bias), wave-uniform
// broadcast, feeding 160 FMAs (2x the FMA/DS density of R8 -> LDS pipe off
// the critical path). waves_per_eu(2,3) gives the ~140-reg live set real
// VGPRs (R7/R8: VGPR=36/60 forced AGPR shuttling / issue bloat). No explicit
// ping-pong: compiler pipelines in-order LDS reads via fine-grained lgkmcnt.
// Argmax purely per-lane (ascending v, strict >); 4 packed-u64 atomicMax.
// ---------------------------------------------------------------------------
__global__ __launch_bounds__(256)
__attribute__((amdgpu_waves_per_eu(2, 3)))
void k_logits(const float* __restrict__ ws, const float* __restrict__ Wio,
              const float* __restrict__ bio, unsigned long long* __restrict__ amax) {
    __shared__ float Wl[VSL * 20];   // 20 KB, row-major [v][20]
    __shared__ float Bl[VSL];        // 1 KB

    int tid = threadIdx.x;
    int sl  = blockIdx.x % 500;      // v-slice
    int tt  = blockIdx.x / 500;      // t-tile
    int v0  = sl * VSL;

    // ---- stage W slice: 1280 float4, 5 per thread (contiguous, coalesced) ----
    {
        const float4* Wg = (const float4*)(Wio + (long long)v0 * 20);
        float4* Wl4 = (float4*)Wl;
#pragma unroll
        for (int r = 0; r < 5; r++) Wl4[tid + 256 * r] = Wg[tid + 256 * r];
        if (tid < 64) ((float4*)Bl)[tid] = ((const float4*)(bio + v0))[tid];
    }
    __syncthreads();

    int t0 = tt * 1024 + tid;        // this thread's t's: t0 + {0,256,512,768}

    // per-thread combined vectors (coalesced: consecutive tid -> consecutive t)
    float c[4][20];
    const float* cmb = ws + OFF_CMB;
#pragma unroll
    for (int k = 0; k < 20; k++) {
#pragma unroll
        for (int q = 0; q < 4; q++) c[q][k] = cmb[k * SEQ + t0 + q * 256];
    }

    float best[4];
    int   bidx[4];
#pragma unroll
    for (int q = 0; q < 4; q++) { best[q] = -3.4e38f; bidx[q] = 0; }

    for (int r = 0; r < VSL; r += 2) {
        float4 w0[5], w1[5];
        {
            const float4* rp0 = (const float4*)(Wl + r * 20);
            const float4* rp1 = (const float4*)(Wl + (r + 1) * 20);
#pragma unroll
            for (int q = 0; q < 5; q++) { w0[q] = rp0[q]; w1[q] = rp1[q]; }
        }
        float2 bb = *(const float2*)(Bl + r);

        // row r
        {
            const float* w = (const float*)w0;
#pragma unroll
            for (int q = 0; q < 4; q++) {
                float a0 = bb.x, a1 = 0.f;
#pragma unroll
                for (int k = 0; k < 10; k++) {
                    a0 += w[k]      * c[q][k];
                    a1 += w[10 + k] * c[q][10 + k];
                }
                float l = a0 + a1;
                if (l > best[q]) { best[q] = l; bidx[q] = v0 + r; }
            }
        }
        // row r+1
        {
            const float* w = (const float*)w1;
#pragma unroll
            for (int q = 0; q < 4; q++) {
                float a0 = bb.y, a1 = 0.f;
#pragma unroll
                for (int k = 0; k < 10; k++) {
                    a0 += w[k]      * c[q][k];
                    a1 += w[10 + k] * c[q][10 + k];
                }
                float l = a0 + a1;
                if (l > best[q]) { best[q] = l; bidx[q] = v0 + r + 1; }
            }
        }
    }

    // per-lane global merge (exact jnp.argmax semantics: max value, lowest idx)
#pragma unroll
    for (int q = 0; q < 4; q++) {
        unsigned int u = __float_as_uint(best[q]);
        unsigned int key = (u & 0x80000000u) ? ~u : (u | 0x80000000u);
        unsigned long long packed =
            ((unsigned long long)key << 32) | (unsigned int)(VOCAB - bidx[q]);
        atomicMax(&amax[t0 + q * 256], packed);
    }
}

// ---------------------------------------------------------------------------
// K5: unpack argmax -> float index
// ---------------------------------------------------------------------------
__global__ void k_out(const unsigned long long* __restrict__ amax,
                      float* __restrict__ out) {
    int t = blockIdx.x * blockDim.x + threadIdx.x;
    if (t >= SEQ) return;
    unsigned long long p = amax[t];
    int idx = VOCAB - (int)(p & 0xFFFFFFFFu);
    out[t] = (float)idx;
}

// ---------------------------------------------------------------------------
extern "C" void kernel_launch(void* const* d_in, const int* in_sizes, int n_in,
                              void* d_out, int out_size, void* d_ws, size_t ws_size,
                              hipStream_t stream) {
    (void)in_sizes; (void)n_in; (void)out_size; (void)ws_size;
    const int*   ix  = (const int*)d_in[0];
    const float* emb = (const float*)d_in[1];
    const float* Wih = (const float*)d_in[2];
    const float* bih = (const float*)d_in[3];
    const float* Wio = (const float*)d_in[4];
    const float* bio = (const float*)d_in[5];
    float* out = (float*)d_out;
    float* ws  = (float*)d_ws;
    unsigned long long* amax = (unsigned long long*)(ws + OFF_AMAX);

    hipLaunchKernelGGL(k_embed,  dim3(SEQ / 256), dim3(256), 0, stream, ix, emb, Wih, bih, ws);
    hipLaunchKernelGGL(k_scan,   dim3(1), dim3(128), 0, stream, Wih, ws);
    hipLaunchKernelGGL(k_logits, dim3(4000), dim3(256), 0, stream, ws, Wio, bio, amax);
    hipLaunchKernelGGL(k_out,    dim3(SEQ / 256), dim3(256), 0, stream, amax, out);
}